// Round 8
// baseline (658.811 us; speedup 1.0000x reference)
//
#include <hip/hip_runtime.h>
#include <hip/hip_bf16.h>

// Problem dims
#define D_IN  1024
#define HID   256
#define OUT_D 128

using bf16x8  = __attribute__((ext_vector_type(8))) short;
using bf16x4  = __attribute__((ext_vector_type(4))) short;
using f32x4   = __attribute__((ext_vector_type(4))) float;
typedef unsigned int u32;

__device__ inline float bf2f(short s) {
    unsigned u = ((unsigned)(unsigned short)s) << 16;
    return __uint_as_float(u);
}
__device__ inline short f2bf(float f) {
    __hip_bfloat16 h = __float2bfloat16(f);   // RNE
    return *reinterpret_cast<short*>(&h);
}

// ---------------------------------------------------------------------------
// pack_all: all 8 weight transposes (f32 [K][N] -> bf16 [n][K]) + bias concat
// ---------------------------------------------------------------------------
__global__ void pack_all(
    const float* __restrict__ W_ui, const float* __restrict__ W_dm,
    const float* __restrict__ W_di, const float* __restrict__ W_um,
    const float* __restrict__ W_uu, const float* __restrict__ W_du,
    const float* __restrict__ W_up, const float* __restrict__ W_dp,
    const float* __restrict__ b_ui, const float* __restrict__ b_dm,
    const float* __restrict__ b_di, const float* __restrict__ b_um,
    short* __restrict__ Wut, short* __restrict__ Wdt,
    short* __restrict__ Wuut, short* __restrict__ Wdut,
    short* __restrict__ Wupt, short* __restrict__ Wdpt,
    float* __restrict__ bu, float* __restrict__ bd)
{
    const int z = blockIdx.z;
    const int tx = threadIdx.x, ty = threadIdx.y;
    if (z == 8) {  // biases
        if (blockIdx.x != 0 || blockIdx.y != 0) return;
        int t = ty * 32 + tx;  // 0..255
        bu[t] = b_ui[t]; bu[256 + t] = b_dm[t];
        bd[t] = b_di[t]; bd[256 + t] = b_um[t];
        return;
    }
    const float* in; short* out; int K, N, n_off = 0;
    switch (z) {
        case 0: in = W_ui; out = Wut;  K = 1024; N = 256; n_off = 0;   break;
        case 1: in = W_dm; out = Wut;  K = 1024; N = 256; n_off = 256; break;
        case 2: in = W_di; out = Wdt;  K = 1024; N = 256; n_off = 0;   break;
        case 3: in = W_um; out = Wdt;  K = 1024; N = 256; n_off = 256; break;
        case 4: in = W_uu; out = Wuut; K = 256;  N = 256; break;
        case 5: in = W_du; out = Wdut; K = 256;  N = 256; break;
        case 6: in = W_up; out = Wupt; K = 256;  N = 128; break;
        default:in = W_dp; out = Wdpt; K = 256;  N = 128; break;
    }
    const int n0 = blockIdx.x * 32, k0 = blockIdx.y * 32;
    if (n0 >= N || k0 >= K) return;
    __shared__ float t[32][33];
#pragma unroll
    for (int j = 0; j < 32; j += 8)
        t[ty + j][tx] = in[(size_t)(k0 + ty + j) * N + (n0 + tx)];
    __syncthreads();
#pragma unroll
    for (int j = 0; j < 32; j += 8)
        out[(size_t)(n_off + n0 + ty + j) * K + (k0 + tx)] = f2bf(t[tx][ty + j]);
}

// ---------------------------------------------------------------------------
// LDS-FREE direct-fragment MFMA GEMM.
//   C[M,N] = (relu?)(A[M,K] @ Wt^T + bias); Wt bf16 [N][K]; A f32 or bf16.
//   BM=BN=128, 256 thr (4 waves 2x2), wave tile 64x64 = 4x4 frags of
//   v_mfma_f32_16x16x32_bf16. Fragments are loaded DIRECTLY from global
//   (B is L2-hot <=1MB; A rows L1/LLC-backed), f32 cvt'd in registers.
//   No LDS, no barriers: waves fully async; 2-step static register
//   ping-pong prefetch (rule #20: compile-time indices only).
//   Requires: K % 64 == 0 (T even), N % 128 == 0.
//   Bijective XCD chunk swizzle, n-fastest (A-panel siblings share L2).
// ---------------------------------------------------------------------------
template <bool RELU, bool AF32, bool CF32>
__global__ __launch_bounds__(256, AF32 ? 2 : 3) void mfma_gemm_direct(
    const void* __restrict__ A_, int lda,
    const short* __restrict__ Wt,
    const float* __restrict__ bias,
    void* __restrict__ Cvoid, int M, int N, int K, int nN)
{
    const int tid = threadIdx.x;

    // bijective XCD chunk swizzle (m204)
    const int nwg = gridDim.x;
    const int orig = blockIdx.x;
    const int qq = nwg >> 3, rr = nwg & 7;
    const int xcd = orig & 7, pos = orig >> 3;
    const int wg = (xcd < rr) ? (xcd * (qq + 1) + pos)
                              : (rr * (qq + 1) + (xcd - rr) * qq + pos);
    const int n0 = (wg % nN) * 128;
    const int m0 = (wg / nN) * 128;

    const int w = tid >> 6, l = tid & 63;
    const int wm = (w >> 1) * 64, wn = (w & 1) * 64;
    const int fr = l & 15, fg = l >> 4;

    f32x4 acc[4][4] = {};

    const char* Ab = (const char*)A_;
    const char* Bb = (const char*)Wt;
    const size_t lda_b = (size_t)lda * (AF32 ? 4 : 2);
    const size_t ldb_b = (size_t)K * 2;

    // per-lane fragment base byte offsets (row clamped for M tail)
    size_t aoff[4];
    size_t boff[4];
#pragma unroll
    for (int i = 0; i < 4; ++i) {
        int r = m0 + wm + i * 16 + fr;
        if (r > M - 1) r = M - 1;
        aoff[i] = (size_t)r * lda_b + (size_t)fg * (AF32 ? 32 : 16);
    }
#pragma unroll
    for (int j = 0; j < 4; ++j) {
        int r = n0 + wn + j * 16 + fr;
        boff[j] = (size_t)r * ldb_b + (size_t)fg * 16;
    }

    const int T = K / 32;   // even for all uses (K = 1024 or 256)

// ---- load/compute macros (static register sets; no runtime indexing) ----
#define LOADB(BR, k0_) \
    _Pragma("unroll") for (int j_ = 0; j_ < 4; ++j_) \
        BR[j_] = *(const bf16x8*)(Bb + boff[j_] + (size_t)(k0_) * 2);

#define LOADA32(AR, k0_) \
    _Pragma("unroll") for (int i_ = 0; i_ < 4; ++i_) { \
        AR[i_][0] = *(const f32x4*)(Ab + aoff[i_] + (size_t)(k0_) * 4); \
        AR[i_][1] = *(const f32x4*)(Ab + aoff[i_] + (size_t)(k0_) * 4 + 16); }

#define LOADA16(AR, k0_) \
    _Pragma("unroll") for (int i_ = 0; i_ < 4; ++i_) \
        AR[i_] = *(const bf16x8*)(Ab + aoff[i_] + (size_t)(k0_) * 2);

#define COMPUTE32(AR, BR) \
    _Pragma("unroll") for (int i_ = 0; i_ < 4; ++i_) { \
        bf16x8 af_; \
        af_[0] = f2bf(AR[i_][0][0]); af_[1] = f2bf(AR[i_][0][1]); \
        af_[2] = f2bf(AR[i_][0][2]); af_[3] = f2bf(AR[i_][0][3]); \
        af_[4] = f2bf(AR[i_][1][0]); af_[5] = f2bf(AR[i_][1][1]); \
        af_[6] = f2bf(AR[i_][1][2]); af_[7] = f2bf(AR[i_][1][3]); \
        _Pragma("unroll") for (int j_ = 0; j_ < 4; ++j_) \
            acc[i_][j_] = __builtin_amdgcn_mfma_f32_16x16x32_bf16( \
                af_, BR[j_], acc[i_][j_], 0, 0, 0); }

#define COMPUTE16(AR, BR) \
    _Pragma("unroll") for (int i_ = 0; i_ < 4; ++i_) \
        _Pragma("unroll") for (int j_ = 0; j_ < 4; ++j_) \
            acc[i_][j_] = __builtin_amdgcn_mfma_f32_16x16x32_bf16( \
                AR[i_], BR[j_], acc[i_][j_], 0, 0, 0);

    if constexpr (AF32) {
        f32x4 aA[4][2], aB[4][2];
        bf16x8 bA[4], bB[4];
        LOADA32(aA, 0) LOADB(bA, 0)
        for (int t = 0; t < T; t += 2) {
            const int k1 = (t + 1) * 32;
            LOADA32(aB, k1) LOADB(bB, k1)
            COMPUTE32(aA, bA)
            if (t + 2 < T) {
                const int k2 = (t + 2) * 32;
                LOADA32(aA, k2) LOADB(bA, k2)
            }
            COMPUTE32(aB, bB)
        }
    } else {
        bf16x8 aA[4], aB[4];
        bf16x8 bA[4], bB[4];
        LOADA16(aA, 0) LOADB(bA, 0)
        for (int t = 0; t < T; t += 2) {
            const int k1 = (t + 1) * 32;
            LOADA16(aB, k1) LOADB(bB, k1)
            COMPUTE16(aA, bA)
            if (t + 2 < T) {
                const int k2 = (t + 2) * 32;
                LOADA16(aA, k2) LOADB(bA, k2)
            }
            COMPUTE16(aB, bB)
        }
    }
#undef LOADB
#undef LOADA32
#undef LOADA16
#undef COMPUTE32
#undef COMPUTE16

    // epilogue: C/D layout col=lane&15, row=(lane>>4)*4+reg  [m89-verified]
#pragma unroll
    for (int i = 0; i < 4; ++i) {
#pragma unroll
        for (int e = 0; e < 4; ++e) {
            int gm = m0 + wm + i * 16 + fg * 4 + e;
            if (gm >= M) continue;
#pragma unroll
            for (int j = 0; j < 4; ++j) {
                int gn = n0 + wn + j * 16 + fr;
                float v = acc[i][j][e] + bias[gn];
                if (RELU) v = fmaxf(v, 0.f);
                if (CF32) ((float*)Cvoid)[(size_t)gm * N + gn] = v;
                else      ((short*)Cvoid)[(size_t)gm * N + gn] = f2bf(v);
            }
        }
    }
}

// ---------------------------------------------------------------------------
// CSR construction, fused: one hist, one scan (2 blocks), one fill
// ---------------------------------------------------------------------------
__global__ void hist2(const int* __restrict__ eu, const int* __restrict__ ed,
                      int* __restrict__ cu, int* __restrict__ cd, int E)
{
    int i = blockIdx.x * blockDim.x + threadIdx.x;
    if (i < E) atomicAdd(&cu[eu[i]], 1);
    else if (i < 2 * E) atomicAdd(&cd[ed[i - E]], 1);
}

__global__ __launch_bounds__(1024) void scan2(
    const int* __restrict__ cnt_u, int* __restrict__ offs_u, int U,
    const int* __restrict__ cnt_d, int* __restrict__ offs_d, int D)
{
    const int* cnt = (blockIdx.x == 0) ? cnt_u : cnt_d;
    int* offs      = (blockIdx.x == 0) ? offs_u : offs_d;
    const int n    = (blockIdx.x == 0) ? U : D;

    __shared__ int tsum[1024];
    const int t = threadIdx.x;
    const int chunk = (n + 1023) / 1024;
    const int lo = t * chunk;
    const int hi = min(lo + chunk, n);
    int s = 0;
    for (int i = lo; i < hi; ++i) s += cnt[i];
    tsum[t] = s;
    __syncthreads();
    for (int d = 1; d < 1024; d <<= 1) {
        int v = (t >= d) ? tsum[t - d] : 0;
        __syncthreads();
        tsum[t] += v;
        __syncthreads();
    }
    int run = (t > 0) ? tsum[t - 1] : 0;
    for (int i = lo; i < hi; ++i) {
        offs[i] = run;
        run += cnt[i];
    }
}

// mutates offs -> segment END; srclist grouped by dst
__global__ void fill2(const int* __restrict__ eu, const int* __restrict__ ed,
                      int* __restrict__ offs_u, int* __restrict__ srcl_u,
                      int* __restrict__ offs_d, int* __restrict__ srcl_d, int E)
{
    int i = blockIdx.x * blockDim.x + threadIdx.x;
    if (i < E) {
        int p = atomicAdd(&offs_u[eu[i]], 1);
        srcl_u[p] = ed[i];
    } else if (i < 2 * E) {
        int k = i - E;
        int p = atomicAdd(&offs_d[ed[k]], 1);
        srcl_d[p] = eu[k];
    }
}

// ---------------------------------------------------------------------------
// Segment sum, both directions in one launch; 1 wave/row, 4-deep gather unroll
// ---------------------------------------------------------------------------
__global__ __launch_bounds__(256) void seg_sum_both(
    const short* __restrict__ dish_msg, const short* __restrict__ user_msg,
    const int* __restrict__ srcl_u, const int* __restrict__ offs_u,
    const int* __restrict__ cnt_u,
    const int* __restrict__ srcl_d, const int* __restrict__ offs_d,
    const int* __restrict__ cnt_d,
    short* __restrict__ user_buf, short* __restrict__ dish_buf,
    int U, int D, int nbU)
{
    const short* msg; const int *sl, *oe, *ct; short* acc; int nRows, rb;
    if (blockIdx.x < nbU) {
        msg = dish_msg; sl = srcl_u; oe = offs_u; ct = cnt_u;
        acc = user_buf; nRows = U; rb = blockIdx.x;
    } else {
        msg = user_msg; sl = srcl_d; oe = offs_d; ct = cnt_d;
        acc = dish_buf; nRows = D; rb = blockIdx.x - nbU;
    }
    int row = rb * 4 + (threadIdx.x >> 6);
    if (row >= nRows) return;
    const int lane = threadIdx.x & 63;
    const int deg = ct[row];
    if (deg == 0) return;
    const int base = oe[row] - deg;

    float s0 = 0.f, s1 = 0.f, s2 = 0.f, s3 = 0.f;
    int j = 0;
    for (; j + 4 <= deg; j += 4) {
        int i0 = sl[base + j], i1 = sl[base + j + 1];
        int i2 = sl[base + j + 2], i3 = sl[base + j + 3];
        bf16x4 v0 = *(const bf16x4*)&msg[(size_t)i0 * 512 + lane * 4];
        bf16x4 v1 = *(const bf16x4*)&msg[(size_t)i1 * 512 + lane * 4];
        bf16x4 v2 = *(const bf16x4*)&msg[(size_t)i2 * 512 + lane * 4];
        bf16x4 v3 = *(const bf16x4*)&msg[(size_t)i3 * 512 + lane * 4];
        s0 += bf2f(v0[0]) + bf2f(v1[0]) + bf2f(v2[0]) + bf2f(v3[0]);
        s1 += bf2f(v0[1]) + bf2f(v1[1]) + bf2f(v2[1]) + bf2f(v3[1]);
        s2 += bf2f(v0[2]) + bf2f(v1[2]) + bf2f(v2[2]) + bf2f(v3[2]);
        s3 += bf2f(v0[3]) + bf2f(v1[3]) + bf2f(v2[3]) + bf2f(v3[3]);
    }
    for (; j < deg; ++j) {
        int i0 = sl[base + j];
        bf16x4 v = *(const bf16x4*)&msg[(size_t)i0 * 512 + lane * 4];
        s0 += bf2f(v[0]); s1 += bf2f(v[1]); s2 += bf2f(v[2]); s3 += bf2f(v[3]);
    }
    bf16x4 c = *(bf16x4*)&acc[(size_t)row * 512 + lane * 4];
    c[0] = f2bf(bf2f(c[0]) + s0);
    c[1] = f2bf(bf2f(c[1]) + s1);
    c[2] = f2bf(bf2f(c[2]) + s2);
    c[3] = f2bf(bf2f(c[3]) + s3);
    *(bf16x4*)&acc[(size_t)row * 512 + lane * 4] = c;
}

extern "C" void kernel_launch(void* const* d_in, const int* in_sizes, int n_in,
                              void* d_out, int out_size, void* d_ws, size_t ws_size,
                              hipStream_t stream)
{
    const float* user_feat = (const float*)d_in[0];
    const float* dish_feat = (const float*)d_in[1];
    const int*   edge_user = (const int*)d_in[2];
    const int*   edge_dish = (const int*)d_in[3];
    const float* W_ui = (const float*)d_in[4];  const float* b_ui = (const float*)d_in[5];
    const float* W_di = (const float*)d_in[6];  const float* b_di = (const float*)d_in[7];
    const float* W_um = (const float*)d_in[8];  const float* b_um = (const float*)d_in[9];
    const float* W_dm = (const float*)d_in[10]; const float* b_dm = (const float*)d_in[11];
    const float* W_uu = (const float*)d_in[12]; const float* b_uu = (const float*)d_in[13];
    const float* W_du = (const float*)d_in[14]; const float* b_du = (const float*)d_in[15];
    const float* W_up = (const float*)d_in[16]; const float* b_up = (const float*)d_in[17];
    const float* W_dp = (const float*)d_in[18]; const float* b_dp = (const float*)d_in[19];

    const int U = in_sizes[0] / D_IN;   // 50000
    const int D = in_sizes[1] / D_IN;   // 10000
    const int E = in_sizes[2];          // 200000

    float* out = (float*)d_out;
    float* user_emb = out;
    float* dish_emb = out + (size_t)U * OUT_D;

    // ---- workspace layout (shorts) ----
    short* sws = (short*)d_ws;
    short* user_buf = sws;                                  // [U][512]: init | msg
    short* dish_buf = user_buf + (size_t)U * 512;           // [D][512]
    short* user_upd = dish_buf + (size_t)D * 512;           // [U][256]
    short* dish_upd = user_upd + (size_t)U * 256;           // [D][256]
    short* Wut  = dish_upd + (size_t)D * 256;               // [512][1024]
    short* Wdt  = Wut  + (size_t)512 * 1024;                // [512][1024]
    short* Wuut = Wdt  + (size_t)512 * 1024;                // [256][256]
    short* Wdut = Wuut + (size_t)256 * 256;                 // [256][256]
    short* Wupt = Wdut + (size_t)256 * 256;                 // [128][256]
    short* Wdpt = Wupt + (size_t)128 * 256;                 // [128][256]
    float* bu   = (float*)(Wdpt + (size_t)128 * 256);       // [512]
    float* bd   = bu + 512;                                 // [512]
    int*   cnt_u  = (int*)(bd + 512);                       // [U]  \ contiguous for
    int*   cnt_d  = cnt_u + U;                              // [D]  / single memset
    int*   offs_u = cnt_d + D;                              // [U]
    int*   offs_d = offs_u + U;                             // [D]
    int*   srcl_u = offs_d + D;                             // [E]
    int*   srcl_d = srcl_u + E;                             // [E]

    // ---- 1: pack all weights + biases ----
    hipLaunchKernelGGL(pack_all, dim3(8, 32, 9), dim3(32, 8), 0, stream,
                       W_ui, W_dm, W_di, W_um, W_uu, W_du, W_up, W_dp,
                       b_ui, b_dm, b_di, b_um,
                       Wut, Wdt, Wuut, Wdut, Wupt, Wdpt, bu, bd);

    // ---- 2-5: CSR build ----
    hipMemsetAsync(cnt_u, 0, (size_t)(U + D) * sizeof(int), stream);
    int eg2 = (2 * E + 255) / 256;
    hipLaunchKernelGGL(hist2, dim3(eg2), dim3(256), 0, stream,
                       edge_user, edge_dish, cnt_u, cnt_d, E);
    hipLaunchKernelGGL(scan2, dim3(2), dim3(1024), 0, stream,
                       cnt_u, offs_u, U, cnt_d, offs_d, D);
    hipLaunchKernelGGL(fill2, dim3(eg2), dim3(256), 0, stream,
                       edge_user, edge_dish, offs_u, srcl_u, offs_d, srcl_d, E);

    // ---- 6-7: big fused projections, f32 A direct (cvt in regs) ----
    hipLaunchKernelGGL((mfma_gemm_direct<true, true, false>),
                       dim3(((U + 127) / 128) * 4), dim3(256), 0, stream,
                       user_feat, D_IN, Wut, bu, user_buf, U, 512, D_IN, 4);
    hipLaunchKernelGGL((mfma_gemm_direct<true, true, false>),
                       dim3(((D + 127) / 128) * 4), dim3(256), 0, stream,
                       dish_feat, D_IN, Wdt, bd, dish_buf, D, 512, D_IN, 4);

    // ---- 8: aggregation, both directions ----
    int nbU = (U + 3) / 4;
    hipLaunchKernelGGL(seg_sum_both, dim3(nbU + (D + 3) / 4), dim3(256), 0, stream,
                       dish_buf + HID, user_buf + HID,
                       srcl_u, offs_u, cnt_u, srcl_d, offs_d, cnt_d,
                       user_buf, dish_buf, U, D, nbU);

    // ---- 9-10: updates (bf16 A, lda=512) ----
    hipLaunchKernelGGL((mfma_gemm_direct<true, false, false>),
                       dim3(((U + 127) / 128) * 2), dim3(256), 0, stream,
                       user_buf, 512, Wuut, b_uu, user_upd, U, HID, HID, 2);
    hipLaunchKernelGGL((mfma_gemm_direct<true, false, false>),
                       dim3(((D + 127) / 128) * 2), dim3(256), 0, stream,
                       dish_buf, 512, Wdut, b_du, dish_upd, D, HID, HID, 2);

    // ---- 11-12: final projections (f32 out) ----
    hipLaunchKernelGGL((mfma_gemm_direct<false, false, true>),
                       dim3((U + 127) / 128), dim3(256), 0, stream,
                       user_upd, HID, Wupt, b_up, user_emb, U, OUT_D, HID, 1);
    hipLaunchKernelGGL((mfma_gemm_direct<false, false, true>),
                       dim3((D + 127) / 128), dim3(256), 0, stream,
                       dish_upd, HID, Wdpt, b_dp, dish_emb, D, OUT_D, HID, 1);
}

// Round 11
// 468.114 us; speedup vs baseline: 1.4074x; 1.4074x over previous
//
#include <hip/hip_runtime.h>
#include <hip/hip_bf16.h>

// Problem dims
#define D_IN  1024
#define HID   256
#define OUT_D 128

using bf16x8  = __attribute__((ext_vector_type(8))) short;
using bf16x4  = __attribute__((ext_vector_type(4))) short;
using f32x4   = __attribute__((ext_vector_type(4))) float;
typedef unsigned int u32;

__device__ inline float bf2f(short s) {
    unsigned u = ((unsigned)(unsigned short)s) << 16;
    return __uint_as_float(u);
}
__device__ inline short f2bf(float f) {
    __hip_bfloat16 h = __float2bfloat16(f);   // RNE
    return *reinterpret_cast<short*>(&h);
}

// async global->LDS, 16 B per lane (HW: wave-uniform LDS base + lane*16)
__device__ __forceinline__ void gld16(void* lds, const void* g) {
    __builtin_amdgcn_global_load_lds(
        (const __attribute__((address_space(1))) u32*)g,
        (__attribute__((address_space(3))) u32*)lds, 16, 0, 0);
}

// ---------------------------------------------------------------------------
// pack_all: all 8 weight transposes (f32 [K][N] -> bf16 [n][K]) + bias concat
// ---------------------------------------------------------------------------
__global__ void pack_all(
    const float* __restrict__ W_ui, const float* __restrict__ W_dm,
    const float* __restrict__ W_di, const float* __restrict__ W_um,
    const float* __restrict__ W_uu, const float* __restrict__ W_du,
    const float* __restrict__ W_up, const float* __restrict__ W_dp,
    const float* __restrict__ b_ui, const float* __restrict__ b_dm,
    const float* __restrict__ b_di, const float* __restrict__ b_um,
    short* __restrict__ Wut, short* __restrict__ Wdt,
    short* __restrict__ Wuut, short* __restrict__ Wdut,
    short* __restrict__ Wupt, short* __restrict__ Wdpt,
    float* __restrict__ bu, float* __restrict__ bd)
{
    const int z = blockIdx.z;
    const int tx = threadIdx.x, ty = threadIdx.y;
    if (z == 8) {  // biases
        if (blockIdx.x != 0 || blockIdx.y != 0) return;
        int t = ty * 32 + tx;  // 0..255
        bu[t] = b_ui[t]; bu[256 + t] = b_dm[t];
        bd[t] = b_di[t]; bd[256 + t] = b_um[t];
        return;
    }
    const float* in; short* out; int K, N, n_off = 0;
    switch (z) {
        case 0: in = W_ui; out = Wut;  K = 1024; N = 256; n_off = 0;   break;
        case 1: in = W_dm; out = Wut;  K = 1024; N = 256; n_off = 256; break;
        case 2: in = W_di; out = Wdt;  K = 1024; N = 256; n_off = 0;   break;
        case 3: in = W_um; out = Wdt;  K = 1024; N = 256; n_off = 256; break;
        case 4: in = W_uu; out = Wuut; K = 256;  N = 256; break;
        case 5: in = W_du; out = Wdut; K = 256;  N = 256; break;
        case 6: in = W_up; out = Wupt; K = 256;  N = 128; break;
        default:in = W_dp; out = Wdpt; K = 256;  N = 128; break;
    }
    const int n0 = blockIdx.x * 32, k0 = blockIdx.y * 32;
    if (n0 >= N || k0 >= K) return;
    __shared__ float t[32][33];
#pragma unroll
    for (int j = 0; j < 32; j += 8)
        t[ty + j][tx] = in[(size_t)(k0 + ty + j) * N + (n0 + tx)];
    __syncthreads();
#pragma unroll
    for (int j = 0; j < 32; j += 8)
        out[(size_t)(n_off + n0 + ty + j) * K + (k0 + tx)] = f2bf(t[tx][ty + j]);
}

// ---------------------------------------------------------------------------
// MFMA GEMM, reg-staged A (issue-early / write-late, T14) + gld16 dbuf B.
//   Per K-step: compute(t) | sync#1 (drains prefetch t+1, issued a full
//   phase ago -> latency hidden) | writeA(t+1) | sync#2 (no VMEM in between,
//   so its vmcnt(0) drain is free) | issue prefetch(t+2).
//   BM=BN=128, BK=64, 256 thr (4 waves 2x2), v_mfma_f32_16x16x32_bf16.
//   A LDS image is ALWAYS bf16 [128][64] (16KB); f32 A cvt'd in regs.
//   B: gld16 double-buffer (2x16KB, 4 gld16/thread -- FULL 16KB coverage;
//      R9/R10's i<2 staged only half the tile -> NaN), linear dest +
//      pre-swizzled source (rule #21).
//   Swizzle byte = row*128 + ((slot*16) ^ ((row&7)<<4)): conflict-free
//   (8 lanes/bank-group on both ds_write_b128 and ds_read_b128 patterns).
//   LDS 48KB -> 3 blk/CU. Bijective XCD chunk swizzle, n-fastest.
// ---------------------------------------------------------------------------
template <bool RELU, bool AF32, bool CF32>
__global__ __launch_bounds__(256) void mfma_gemm_rs(
    const void* __restrict__ A_, int lda,
    const short* __restrict__ Wt,
    const float* __restrict__ bias,
    void* __restrict__ Cvoid, int M, int N, int K, int nN)
{
    __shared__ __align__(16) char As[16384];      // A bf16 [128][64], swizzled
    __shared__ __align__(16) char Bs[2][16384];   // B bf16 dbuf, swizzled

    const int tid = threadIdx.x;

    // bijective XCD chunk swizzle (m204)
    const int nwg = gridDim.x;
    const int orig = blockIdx.x;
    const int qq = nwg >> 3, rr = nwg & 7;
    const int xcd = orig & 7, pos = orig >> 3;
    const int wg = (xcd < rr) ? (xcd * (qq + 1) + pos)
                              : (rr * (qq + 1) + (xcd - rr) * qq + pos);
    const int n0 = (wg % nN) * 128;
    const int m0 = (wg / nN) * 128;

    const int w = tid >> 6, l = tid & 63;
    const int wm = (w >> 1) * 64, wn = (w & 1) * 64;
    const int fr = l & 15, fg = l >> 4;

    f32x4 acc[4][4] = {};

    const char* Ab = (const char*)A_;
    const char* Bb = (const char*)Wt;
    const size_t lda_b = (size_t)lda * (AF32 ? 4 : 2);
    const size_t ldb_b = (size_t)K * 2;

    // A staging map: thread t covers bf16-image row r = t>>1, half h = t&1
    const int r_st = tid >> 1, h_st = tid & 1;
    int arow = m0 + r_st; if (arow > M - 1) arow = M - 1;
    const char* aSrcRow = Ab + (size_t)arow * lda_b;

    f32x4  gA32[8];
    bf16x8 gA16[4];

    auto issueA = [&](int k0) {
        if constexpr (AF32) {
            const char* p = aSrcRow + (size_t)k0 * 4 + h_st * 128;
#pragma unroll
            for (int q = 0; q < 8; ++q) gA32[q] = *(const f32x4*)(p + q * 16);
        } else {
            const char* p = aSrcRow + (size_t)k0 * 2 + h_st * 64;
#pragma unroll
            for (int q = 0; q < 4; ++q) gA16[q] = *(const bf16x8*)(p + q * 16);
        }
    };
    auto writeA = [&]() {
#pragma unroll
        for (int q = 0; q < 4; ++q) {
            int slot = h_st * 4 + q;
            int byte = r_st * 128 + ((slot * 16) ^ ((r_st & 7) << 4));
            bf16x8 v;
            if constexpr (AF32) {
                f32x4 lo = gA32[2 * q], hi = gA32[2 * q + 1];
                v[0] = f2bf(lo[0]); v[1] = f2bf(lo[1]);
                v[2] = f2bf(lo[2]); v[3] = f2bf(lo[3]);
                v[4] = f2bf(hi[0]); v[5] = f2bf(hi[1]);
                v[6] = f2bf(hi[2]); v[7] = f2bf(hi[3]);
            } else {
                v = gA16[q];
            }
            *(bf16x8*)(As + byte) = v;
        }
    };
    auto stageB = [&](int buf, int k0) {
#pragma unroll
        for (int i = 0; i < 4; ++i) {              // FULL 16KB: 4 x 4096
            int o = i * 4096 + tid * 16;
            int row = o >> 7, cb = o & 127;
            int scb = cb ^ ((row & 7) << 4);       // pre-swizzled source
            gld16(Bs[buf] + o, Bb + (size_t)(n0 + row) * ldb_b + (size_t)k0 * 2 + scb);
        }
    };

    const int T = K / 64;

    // ---- prologue: stage tile 0, then issue tile-1 prefetch ----
    issueA(0); stageB(0, 0);
    writeA();                    // waits gA regs via data dep
    __syncthreads();             // drains stageB(0) vmcnt + writeA lgkm
    if (T > 1) { issueA(64); stageB(1, 64); }

    int cur = 0;
    for (int t = 0; t < T; ++t) {
        const char* Bc = Bs[cur];
#pragma unroll
        for (int kk = 0; kk < 2; ++kk) {
            bf16x8 af[4], bfv[4];
#pragma unroll
            for (int i = 0; i < 4; ++i) {
                int row = wm + i * 16 + fr;
                int cb = row * 128 + (((kk * 4 + fg) * 16) ^ ((row & 7) << 4));
                af[i] = *reinterpret_cast<const bf16x8*>(As + cb);
            }
#pragma unroll
            for (int j = 0; j < 4; ++j) {
                int row = wn + j * 16 + fr;
                int cb = row * 128 + (((kk * 4 + fg) * 16) ^ ((row & 7) << 4));
                bfv[j] = *reinterpret_cast<const bf16x8*>(Bc + cb);
            }
#pragma unroll
            for (int i = 0; i < 4; ++i)
#pragma unroll
                for (int j = 0; j < 4; ++j)
                    acc[i][j] = __builtin_amdgcn_mfma_f32_16x16x32_bf16(
                        af[i], bfv[j], acc[i][j], 0, 0, 0);
        }

        if (t + 1 < T) {
            __syncthreads();     // #1: prefetch(t+1) landed (issued a full
                                 //     phase ago); all waves done reading
            writeA();            // As = A(t+1) (bf16 cvt in regs)
            __syncthreads();     // #2: writes visible; vmcnt already 0 -> free
            if (t + 2 < T) { issueA((t + 2) * 64); stageB(cur, (t + 2) * 64); }
            cur ^= 1;
        }
    }

    // epilogue: C/D layout col=lane&15, row=(lane>>4)*4+reg  [m89-verified]
#pragma unroll
    for (int i = 0; i < 4; ++i) {
#pragma unroll
        for (int e = 0; e < 4; ++e) {
            int gm = m0 + wm + i * 16 + fg * 4 + e;
            if (gm >= M) continue;
#pragma unroll
            for (int j = 0; j < 4; ++j) {
                int gn = n0 + wn + j * 16 + fr;
                float v = acc[i][j][e] + bias[gn];
                if (RELU) v = fmaxf(v, 0.f);
                if (CF32) ((float*)Cvoid)[(size_t)gm * N + gn] = v;
                else      ((short*)Cvoid)[(size_t)gm * N + gn] = f2bf(v);
            }
        }
    }
}

// ---------------------------------------------------------------------------
// CSR construction, fused: one hist, one scan (2 blocks), one fill
// ---------------------------------------------------------------------------
__global__ void hist2(const int* __restrict__ eu, const int* __restrict__ ed,
                      int* __restrict__ cu, int* __restrict__ cd, int E)
{
    int i = blockIdx.x * blockDim.x + threadIdx.x;
    if (i < E) atomicAdd(&cu[eu[i]], 1);
    else if (i < 2 * E) atomicAdd(&cd[ed[i - E]], 1);
}

__global__ __launch_bounds__(1024) void scan2(
    const int* __restrict__ cnt_u, int* __restrict__ offs_u, int U,
    const int* __restrict__ cnt_d, int* __restrict__ offs_d, int D)
{
    const int* cnt = (blockIdx.x == 0) ? cnt_u : cnt_d;
    int* offs      = (blockIdx.x == 0) ? offs_u : offs_d;
    const int n    = (blockIdx.x == 0) ? U : D;

    __shared__ int tsum[1024];
    const int t = threadIdx.x;
    const int chunk = (n + 1023) / 1024;
    const int lo = t * chunk;
    const int hi = min(lo + chunk, n);
    int s = 0;
    for (int i = lo; i < hi; ++i) s += cnt[i];
    tsum[t] = s;
    __syncthreads();
    for (int d = 1; d < 1024; d <<= 1) {
        int v = (t >= d) ? tsum[t - d] : 0;
        __syncthreads();
        tsum[t] += v;
        __syncthreads();
    }
    int run = (t > 0) ? tsum[t - 1] : 0;
    for (int i = lo; i < hi; ++i) {
        offs[i] = run;
        run += cnt[i];
    }
}

// mutates offs -> segment END; srclist grouped by dst
__global__ void fill2(const int* __restrict__ eu, const int* __restrict__ ed,
                      int* __restrict__ offs_u, int* __restrict__ srcl_u,
                      int* __restrict__ offs_d, int* __restrict__ srcl_d, int E)
{
    int i = blockIdx.x * blockDim.x + threadIdx.x;
    if (i < E) {
        int p = atomicAdd(&offs_u[eu[i]], 1);
        srcl_u[p] = ed[i];
    } else if (i < 2 * E) {
        int k = i - E;
        int p = atomicAdd(&offs_d[ed[k]], 1);
        srcl_d[p] = eu[k];
    }
}

// ---------------------------------------------------------------------------
// Segment sum, both directions in one launch; 1 wave/row, 4-deep gather unroll
// ---------------------------------------------------------------------------
__global__ __launch_bounds__(256) void seg_sum_both(
    const short* __restrict__ dish_msg, const short* __restrict__ user_msg,
    const int* __restrict__ srcl_u, const int* __restrict__ offs_u,
    const int* __restrict__ cnt_u,
    const int* __restrict__ srcl_d, const int* __restrict__ offs_d,
    const int* __restrict__ cnt_d,
    short* __restrict__ user_buf, short* __restrict__ dish_buf,
    int U, int D, int nbU)
{
    const short* msg; const int *sl, *oe, *ct; short* acc; int nRows, rb;
    if (blockIdx.x < nbU) {
        msg = dish_msg; sl = srcl_u; oe = offs_u; ct = cnt_u;
        acc = user_buf; nRows = U; rb = blockIdx.x;
    } else {
        msg = user_msg; sl = srcl_d; oe = offs_d; ct = cnt_d;
        acc = dish_buf; nRows = D; rb = blockIdx.x - nbU;
    }
    int row = rb * 4 + (threadIdx.x >> 6);
    if (row >= nRows) return;
    const int lane = threadIdx.x & 63;
    const int deg = ct[row];
    if (deg == 0) return;
    const int base = oe[row] - deg;

    float s0 = 0.f, s1 = 0.f, s2 = 0.f, s3 = 0.f;
    int j = 0;
    for (; j + 4 <= deg; j += 4) {
        int i0 = sl[base + j], i1 = sl[base + j + 1];
        int i2 = sl[base + j + 2], i3 = sl[base + j + 3];
        bf16x4 v0 = *(const bf16x4*)&msg[(size_t)i0 * 512 + lane * 4];
        bf16x4 v1 = *(const bf16x4*)&msg[(size_t)i1 * 512 + lane * 4];
        bf16x4 v2 = *(const bf16x4*)&msg[(size_t)i2 * 512 + lane * 4];
        bf16x4 v3 = *(const bf16x4*)&msg[(size_t)i3 * 512 + lane * 4];
        s0 += bf2f(v0[0]) + bf2f(v1[0]) + bf2f(v2[0]) + bf2f(v3[0]);
        s1 += bf2f(v0[1]) + bf2f(v1[1]) + bf2f(v2[1]) + bf2f(v3[1]);
        s2 += bf2f(v0[2]) + bf2f(v1[2]) + bf2f(v2[2]) + bf2f(v3[2]);
        s3 += bf2f(v0[3]) + bf2f(v1[3]) + bf2f(v2[3]) + bf2f(v3[3]);
    }
    for (; j < deg; ++j) {
        int i0 = sl[base + j];
        bf16x4 v = *(const bf16x4*)&msg[(size_t)i0 * 512 + lane * 4];
        s0 += bf2f(v[0]); s1 += bf2f(v[1]); s2 += bf2f(v[2]); s3 += bf2f(v[3]);
    }
    bf16x4 c = *(bf16x4*)&acc[(size_t)row * 512 + lane * 4];
    c[0] = f2bf(bf2f(c[0]) + s0);
    c[1] = f2bf(bf2f(c[1]) + s1);
    c[2] = f2bf(bf2f(c[2]) + s2);
    c[3] = f2bf(bf2f(c[3]) + s3);
    *(bf16x4*)&acc[(size_t)row * 512 + lane * 4] = c;
}

extern "C" void kernel_launch(void* const* d_in, const int* in_sizes, int n_in,
                              void* d_out, int out_size, void* d_ws, size_t ws_size,
                              hipStream_t stream)
{
    const float* user_feat = (const float*)d_in[0];
    const float* dish_feat = (const float*)d_in[1];
    const int*   edge_user = (const int*)d_in[2];
    const int*   edge_dish = (const int*)d_in[3];
    const float* W_ui = (const float*)d_in[4];  const float* b_ui = (const float*)d_in[5];
    const float* W_di = (const float*)d_in[6];  const float* b_di = (const float*)d_in[7];
    const float* W_um = (const float*)d_in[8];  const float* b_um = (const float*)d_in[9];
    const float* W_dm = (const float*)d_in[10]; const float* b_dm = (const float*)d_in[11];
    const float* W_uu = (const float*)d_in[12]; const float* b_uu = (const float*)d_in[13];
    const float* W_du = (const float*)d_in[14]; const float* b_du = (const float*)d_in[15];
    const float* W_up = (const float*)d_in[16]; const float* b_up = (const float*)d_in[17];
    const float* W_dp = (const float*)d_in[18]; const float* b_dp = (const float*)d_in[19];

    const int U = in_sizes[0] / D_IN;   // 50000
    const int D = in_sizes[1] / D_IN;   // 10000
    const int E = in_sizes[2];          // 200000

    float* out = (float*)d_out;
    float* user_emb = out;
    float* dish_emb = out + (size_t)U * OUT_D;

    // ---- workspace layout (shorts) ----
    short* sws = (short*)d_ws;
    short* user_buf = sws;                                  // [U][512]: init | msg
    short* dish_buf = user_buf + (size_t)U * 512;           // [D][512]
    short* user_upd = dish_buf + (size_t)D * 512;           // [U][256]
    short* dish_upd = user_upd + (size_t)U * 256;           // [D][256]
    short* Wut  = dish_upd + (size_t)D * 256;               // [512][1024]
    short* Wdt  = Wut  + (size_t)512 * 1024;                // [512][1024]
    short* Wuut = Wdt  + (size_t)512 * 1024;                // [256][256]
    short* Wdut = Wuut + (size_t)256 * 256;                 // [256][256]
    short* Wupt = Wdut + (size_t)256 * 256;                 // [128][256]
    short* Wdpt = Wupt + (size_t)128 * 256;                 // [128][256]
    float* bu   = (float*)(Wdpt + (size_t)128 * 256);       // [512]
    float* bd   = bu + 512;                                 // [512]
    int*   cnt_u  = (int*)(bd + 512);                       // [U]  \ contiguous for
    int*   cnt_d  = cnt_u + U;                              // [D]  / single memset
    int*   offs_u = cnt_d + D;                              // [U]
    int*   offs_d = offs_u + U;                             // [D]
    int*   srcl_u = offs_d + D;                             // [E]
    int*   srcl_d = srcl_u + E;                             // [E]

    // ---- 1: pack all weights + biases ----
    hipLaunchKernelGGL(pack_all, dim3(8, 32, 9), dim3(32, 8), 0, stream,
                       W_ui, W_dm, W_di, W_um, W_uu, W_du, W_up, W_dp,
                       b_ui, b_dm, b_di, b_um,
                       Wut, Wdt, Wuut, Wdut, Wupt, Wdpt, bu, bd);

    // ---- 2-5: CSR build ----
    hipMemsetAsync(cnt_u, 0, (size_t)(U + D) * sizeof(int), stream);
    int eg2 = (2 * E + 255) / 256;
    hipLaunchKernelGGL(hist2, dim3(eg2), dim3(256), 0, stream,
                       edge_user, edge_dish, cnt_u, cnt_d, E);
    hipLaunchKernelGGL(scan2, dim3(2), dim3(1024), 0, stream,
                       cnt_u, offs_u, U, cnt_d, offs_d, D);
    hipLaunchKernelGGL(fill2, dim3(eg2), dim3(256), 0, stream,
                       edge_user, edge_dish, offs_u, srcl_u, offs_d, srcl_d, E);

    // ---- 6-7: big fused projections, f32 A reg-staged (cvt in regs) ----
    hipLaunchKernelGGL((mfma_gemm_rs<true, true, false>),
                       dim3(((U + 127) / 128) * 4), dim3(256), 0, stream,
                       user_feat, D_IN, Wut, bu, user_buf, U, 512, D_IN, 4);
    hipLaunchKernelGGL((mfma_gemm_rs<true, true, false>),
                       dim3(((D + 127) / 128) * 4), dim3(256), 0, stream,
                       dish_feat, D_IN, Wdt, bd, dish_buf, D, 512, D_IN, 4);

    // ---- 8: aggregation, both directions ----
    int nbU = (U + 3) / 4;
    hipLaunchKernelGGL(seg_sum_both, dim3(nbU + (D + 3) / 4), dim3(256), 0, stream,
                       dish_buf + HID, user_buf + HID,
                       srcl_u, offs_u, cnt_u, srcl_d, offs_d, cnt_d,
                       user_buf, dish_buf, U, D, nbU);

    // ---- 9-10: updates (bf16 A, lda=512) ----
    hipLaunchKernelGGL((mfma_gemm_rs<true, false, false>),
                       dim3(((U + 127) / 128) * 2), dim3(256), 0, stream,
                       user_buf, 512, Wuut, b_uu, user_upd, U, HID, HID, 2);
    hipLaunchKernelGGL((mfma_gemm_rs<true, false, false>),
                       dim3(((D + 127) / 128) * 2), dim3(256), 0, stream,
                       dish_buf, 512, Wdut, b_du, dish_upd, D, HID, HID, 2);

    // ---- 11-12: final projections (f32 out) ----
    hipLaunchKernelGGL((mfma_gemm_rs<false, false, true>),
                       dim3((U + 127) / 128), dim3(256), 0, stream,
                       user_upd, HID, Wupt, b_up, user_emb, U, OUT_D, HID, 1);
    hipLaunchKernelGGL((mfma_gemm_rs<false, false, true>),
                       dim3((D + 127) / 128), dim3(256), 0, stream,
                       dish_upd, HID, Wdpt, b_dp, dish_emb, D, OUT_D, HID, 1);
}

// Round 12
// 353.207 us; speedup vs baseline: 1.8652x; 1.3253x over previous
//
#include <hip/hip_runtime.h>
#include <hip/hip_bf16.h>

// Problem dims
#define D_IN  1024
#define HID   256
#define OUT_D 128

using bf16x8  = __attribute__((ext_vector_type(8))) short;
using bf16x4  = __attribute__((ext_vector_type(4))) short;
using f32x4   = __attribute__((ext_vector_type(4))) float;
typedef unsigned int u32;

__device__ inline float bf2f(short s) {
    unsigned u = ((unsigned)(unsigned short)s) << 16;
    return __uint_as_float(u);
}
__device__ inline short f2bf(float f) {
    __hip_bfloat16 h = __float2bfloat16(f);   // RNE
    return *reinterpret_cast<short*>(&h);
}

// async global->LDS, 16 B per lane (HW: wave-uniform LDS base + lane*16)
__device__ __forceinline__ void gld16(void* lds, const void* g) {
    __builtin_amdgcn_global_load_lds(
        (const __attribute__((address_space(1))) u32*)g,
        (__attribute__((address_space(3))) u32*)lds, 16, 0, 0);
}

// ---------------------------------------------------------------------------
// pack_all: all 8 weight transposes (f32 [K][N] -> bf16 [n][K]) + bias concat
// ---------------------------------------------------------------------------
__global__ void pack_all(
    const float* __restrict__ W_ui, const float* __restrict__ W_dm,
    const float* __restrict__ W_di, const float* __restrict__ W_um,
    const float* __restrict__ W_uu, const float* __restrict__ W_du,
    const float* __restrict__ W_up, const float* __restrict__ W_dp,
    const float* __restrict__ b_ui, const float* __restrict__ b_dm,
    const float* __restrict__ b_di, const float* __restrict__ b_um,
    short* __restrict__ Wut, short* __restrict__ Wdt,
    short* __restrict__ Wuut, short* __restrict__ Wdut,
    short* __restrict__ Wupt, short* __restrict__ Wdpt,
    float* __restrict__ bu, float* __restrict__ bd)
{
    const int z = blockIdx.z;
    const int tx = threadIdx.x, ty = threadIdx.y;
    if (z == 8) {  // biases
        if (blockIdx.x != 0 || blockIdx.y != 0) return;
        int t = ty * 32 + tx;  // 0..255
        bu[t] = b_ui[t]; bu[256 + t] = b_dm[t];
        bd[t] = b_di[t]; bd[256 + t] = b_um[t];
        return;
    }
    const float* in; short* out; int K, N, n_off = 0;
    switch (z) {
        case 0: in = W_ui; out = Wut;  K = 1024; N = 256; n_off = 0;   break;
        case 1: in = W_dm; out = Wut;  K = 1024; N = 256; n_off = 256; break;
        case 2: in = W_di; out = Wdt;  K = 1024; N = 256; n_off = 0;   break;
        case 3: in = W_um; out = Wdt;  K = 1024; N = 256; n_off = 256; break;
        case 4: in = W_uu; out = Wuut; K = 256;  N = 256; break;
        case 5: in = W_du; out = Wdut; K = 256;  N = 256; break;
        case 6: in = W_up; out = Wupt; K = 256;  N = 128; break;
        default:in = W_dp; out = Wdpt; K = 256;  N = 128; break;
    }
    const int n0 = blockIdx.x * 32, k0 = blockIdx.y * 32;
    if (n0 >= N || k0 >= K) return;
    __shared__ float t[32][33];
#pragma unroll
    for (int j = 0; j < 32; j += 8)
        t[ty + j][tx] = in[(size_t)(k0 + ty + j) * N + (n0 + tx)];
    __syncthreads();
#pragma unroll
    for (int j = 0; j < 32; j += 8)
        out[(size_t)(n_off + n0 + ty + j) * K + (k0 + tx)] = f2bf(t[tx][ty + j]);
}

// ---------------------------------------------------------------------------
// Dual MFMA GEMM (two independent GEMMs, arg-muxed by block range so the
// small grid fills the big one's tail). Per GEMM: R5-proven structure --
// gld16 staging, single LDS buffer, BK=32 -> 24KB (f32-A) / 16KB (bf16-A)
// -> 6 blocks/CU (2x the TLP of R5's 48KB).
//   Per K-step: stage(6 gld16) | __syncthreads | 16 MFMA | __syncthreads.
//   A: 128B rows, swizzle c ^= (row&7)<<4 (conflict-free, R11-verified).
//   B: 64B rows, swizzle c ^= (row&3)<<4 (~4-way on reads, not critical).
//   gld16: linear LDS dest + pre-swizzled SOURCE (rule #21, involution).
//   Bijective XCD chunk swizzle per sub-grid, n-fastest.
// ---------------------------------------------------------------------------
template <bool RELU, bool AF32, bool CF32>
__global__ __launch_bounds__(256) void mfma_gemm2(
    const void* __restrict__ A0_, int lda0, const short* __restrict__ Wt0,
    const float* __restrict__ bias0, void* __restrict__ C0,
    int M0, int N0, int K0, int nN0, int nb0,
    const void* __restrict__ A1_, int lda1, const short* __restrict__ Wt1,
    const float* __restrict__ bias1, void* __restrict__ C1,
    int M1, int N1, int K1, int nN1)
{
    constexpr int ABYTES = AF32 ? 16384 : 8192;   // 128 rows x 128B / 64B
    constexpr int BBYTES = 8192;                  // 128 rows x 64B
    __shared__ __align__(16) char smem[ABYTES + BBYTES];
    char* As = smem;
    char* Bs = smem + ABYTES;

    const int tid = threadIdx.x;

    // select GEMM by block range
    const void* A_; const short* Wt; const float* bias; void* Cv;
    int lda, M, N, K, nN, nwg, orig;
    if ((int)blockIdx.x < nb0) {
        A_ = A0_; lda = lda0; Wt = Wt0; bias = bias0; Cv = C0;
        M = M0; N = N0; K = K0; nN = nN0; nwg = nb0; orig = blockIdx.x;
    } else {
        A_ = A1_; lda = lda1; Wt = Wt1; bias = bias1; Cv = C1;
        M = M1; N = N1; K = K1; nN = nN1;
        nwg = gridDim.x - nb0; orig = blockIdx.x - nb0;
    }

    // bijective XCD chunk swizzle (m204) within the sub-grid
    const int qq = nwg >> 3, rr = nwg & 7;
    const int xcd = orig & 7, pos = orig >> 3;
    const int wg = (xcd < rr) ? (xcd * (qq + 1) + pos)
                              : (rr * (qq + 1) + (xcd - rr) * qq + pos);
    const int n0 = (wg % nN) * 128;
    const int m0 = (wg / nN) * 128;

    const int w = tid >> 6, l = tid & 63;
    const int wm = (w >> 1) * 64, wn = (w & 1) * 64;
    const int fr = l & 15, fg = l >> 4;

    f32x4 acc[4][4] = {};

    const char* Ab = (const char*)A_;
    const char* Bb = (const char*)Wt;
    const size_t lda_b = (size_t)lda * (AF32 ? 4 : 2);
    const size_t ldb_b = (size_t)K * 2;

    for (int k0 = 0; k0 < K; k0 += 32) {
        // ---- stage A (BK=32) ----
        if constexpr (AF32) {
#pragma unroll
            for (int i = 0; i < 4; ++i) {      // 128 rows x 128B f32
                int o = i * 4096 + tid * 16;
                int row = o >> 7, cb = o & 127;
                int scb = cb ^ ((row & 7) << 4);
                int arow = m0 + row; if (arow > M - 1) arow = M - 1;
                gld16(As + o, Ab + (size_t)arow * lda_b + (size_t)k0 * 4 + scb);
            }
        } else {
#pragma unroll
            for (int i = 0; i < 2; ++i) {      // 128 rows x 64B bf16
                int o = i * 4096 + tid * 16;
                int row = o >> 6, cb = o & 63;
                int scb = cb ^ ((row & 3) << 4);
                int arow = m0 + row; if (arow > M - 1) arow = M - 1;
                gld16(As + o, Ab + (size_t)arow * lda_b + (size_t)k0 * 2 + scb);
            }
        }
        // ---- stage B (128 rows x 64B bf16) ----
#pragma unroll
        for (int i = 0; i < 2; ++i) {
            int o = i * 4096 + tid * 16;
            int row = o >> 6, cb = o & 63;
            int scb = cb ^ ((row & 3) << 4);
            gld16(Bs + o, Bb + (size_t)(n0 + row) * ldb_b + (size_t)k0 * 2 + scb);
        }
        __syncthreads();   // drains vmcnt; tile ready

        bf16x8 af[4], bfv[4];
#pragma unroll
        for (int i = 0; i < 4; ++i) {
            int row = wm + i * 16 + fr;
            if constexpr (AF32) {
                int sw = (row & 7) << 4;
                const char* rb = As + row * 128;
                f32x4 lo = *reinterpret_cast<const f32x4*>(rb + ((fg * 32) ^ sw));
                f32x4 hi = *reinterpret_cast<const f32x4*>(rb + ((fg * 32 + 16) ^ sw));
                bf16x8 t;
                t[0] = f2bf(lo[0]); t[1] = f2bf(lo[1]);
                t[2] = f2bf(lo[2]); t[3] = f2bf(lo[3]);
                t[4] = f2bf(hi[0]); t[5] = f2bf(hi[1]);
                t[6] = f2bf(hi[2]); t[7] = f2bf(hi[3]);
                af[i] = t;
            } else {
                int cb = (fg * 16) ^ ((row & 3) << 4);
                af[i] = *reinterpret_cast<const bf16x8*>(As + row * 64 + cb);
            }
        }
#pragma unroll
        for (int j = 0; j < 4; ++j) {
            int row = wn + j * 16 + fr;
            int cb = (fg * 16) ^ ((row & 3) << 4);
            bfv[j] = *reinterpret_cast<const bf16x8*>(Bs + row * 64 + cb);
        }
#pragma unroll
        for (int i = 0; i < 4; ++i)
#pragma unroll
            for (int j = 0; j < 4; ++j)
                acc[i][j] = __builtin_amdgcn_mfma_f32_16x16x32_bf16(
                    af[i], bfv[j], acc[i][j], 0, 0, 0);

        __syncthreads();   // reads done; next stage may overwrite
    }

    // epilogue: C/D layout col=lane&15, row=(lane>>4)*4+reg  [m89-verified]
#pragma unroll
    for (int i = 0; i < 4; ++i) {
#pragma unroll
        for (int e = 0; e < 4; ++e) {
            int gm = m0 + wm + i * 16 + fg * 4 + e;
            if (gm >= M) continue;
#pragma unroll
            for (int j = 0; j < 4; ++j) {
                int gn = n0 + wn + j * 16 + fr;
                float v = acc[i][j][e] + bias[gn];
                if (RELU) v = fmaxf(v, 0.f);
                if (CF32) ((float*)Cv)[(size_t)gm * N + gn] = v;
                else      ((short*)Cv)[(size_t)gm * N + gn] = f2bf(v);
            }
        }
    }
}

// ---------------------------------------------------------------------------
// CSR construction, fused: one hist, one scan (2 blocks), one fill
// ---------------------------------------------------------------------------
__global__ void hist2(const int* __restrict__ eu, const int* __restrict__ ed,
                      int* __restrict__ cu, int* __restrict__ cd, int E)
{
    int i = blockIdx.x * blockDim.x + threadIdx.x;
    if (i < E) atomicAdd(&cu[eu[i]], 1);
    else if (i < 2 * E) atomicAdd(&cd[ed[i - E]], 1);
}

__global__ __launch_bounds__(1024) void scan2(
    const int* __restrict__ cnt_u, int* __restrict__ offs_u, int U,
    const int* __restrict__ cnt_d, int* __restrict__ offs_d, int D)
{
    const int* cnt = (blockIdx.x == 0) ? cnt_u : cnt_d;
    int* offs      = (blockIdx.x == 0) ? offs_u : offs_d;
    const int n    = (blockIdx.x == 0) ? U : D;

    __shared__ int tsum[1024];
    const int t = threadIdx.x;
    const int chunk = (n + 1023) / 1024;
    const int lo = t * chunk;
    const int hi = min(lo + chunk, n);
    int s = 0;
    for (int i = lo; i < hi; ++i) s += cnt[i];
    tsum[t] = s;
    __syncthreads();
    for (int d = 1; d < 1024; d <<= 1) {
        int v = (t >= d) ? tsum[t - d] : 0;
        __syncthreads();
        tsum[t] += v;
        __syncthreads();
    }
    int run = (t > 0) ? tsum[t - 1] : 0;
    for (int i = lo; i < hi; ++i) {
        offs[i] = run;
        run += cnt[i];
    }
}

// mutates offs -> segment END; srclist grouped by dst
__global__ void fill2(const int* __restrict__ eu, const int* __restrict__ ed,
                      int* __restrict__ offs_u, int* __restrict__ srcl_u,
                      int* __restrict__ offs_d, int* __restrict__ srcl_d, int E)
{
    int i = blockIdx.x * blockDim.x + threadIdx.x;
    if (i < E) {
        int p = atomicAdd(&offs_u[eu[i]], 1);
        srcl_u[p] = ed[i];
    } else if (i < 2 * E) {
        int k = i - E;
        int p = atomicAdd(&offs_d[ed[k]], 1);
        srcl_d[p] = eu[k];
    }
}

// ---------------------------------------------------------------------------
// Segment sum, both directions in one launch; 1 wave/row, 4-deep gather unroll
// ---------------------------------------------------------------------------
__global__ __launch_bounds__(256) void seg_sum_both(
    const short* __restrict__ dish_msg, const short* __restrict__ user_msg,
    const int* __restrict__ srcl_u, const int* __restrict__ offs_u,
    const int* __restrict__ cnt_u,
    const int* __restrict__ srcl_d, const int* __restrict__ offs_d,
    const int* __restrict__ cnt_d,
    short* __restrict__ user_buf, short* __restrict__ dish_buf,
    int U, int D, int nbU)
{
    const short* msg; const int *sl, *oe, *ct; short* acc; int nRows, rb;
    if (blockIdx.x < nbU) {
        msg = dish_msg; sl = srcl_u; oe = offs_u; ct = cnt_u;
        acc = user_buf; nRows = U; rb = blockIdx.x;
    } else {
        msg = user_msg; sl = srcl_d; oe = offs_d; ct = cnt_d;
        acc = dish_buf; nRows = D; rb = blockIdx.x - nbU;
    }
    int row = rb * 4 + (threadIdx.x >> 6);
    if (row >= nRows) return;
    const int lane = threadIdx.x & 63;
    const int deg = ct[row];
    if (deg == 0) return;
    const int base = oe[row] - deg;

    float s0 = 0.f, s1 = 0.f, s2 = 0.f, s3 = 0.f;
    int j = 0;
    for (; j + 4 <= deg; j += 4) {
        int i0 = sl[base + j], i1 = sl[base + j + 1];
        int i2 = sl[base + j + 2], i3 = sl[base + j + 3];
        bf16x4 v0 = *(const bf16x4*)&msg[(size_t)i0 * 512 + lane * 4];
        bf16x4 v1 = *(const bf16x4*)&msg[(size_t)i1 * 512 + lane * 4];
        bf16x4 v2 = *(const bf16x4*)&msg[(size_t)i2 * 512 + lane * 4];
        bf16x4 v3 = *(const bf16x4*)&msg[(size_t)i3 * 512 + lane * 4];
        s0 += bf2f(v0[0]) + bf2f(v1[0]) + bf2f(v2[0]) + bf2f(v3[0]);
        s1 += bf2f(v0[1]) + bf2f(v1[1]) + bf2f(v2[1]) + bf2f(v3[1]);
        s2 += bf2f(v0[2]) + bf2f(v1[2]) + bf2f(v2[2]) + bf2f(v3[2]);
        s3 += bf2f(v0[3]) + bf2f(v1[3]) + bf2f(v2[3]) + bf2f(v3[3]);
    }
    for (; j < deg; ++j) {
        int i0 = sl[base + j];
        bf16x4 v = *(const bf16x4*)&msg[(size_t)i0 * 512 + lane * 4];
        s0 += bf2f(v[0]); s1 += bf2f(v[1]); s2 += bf2f(v[2]); s3 += bf2f(v[3]);
    }
    bf16x4 c = *(bf16x4*)&acc[(size_t)row * 512 + lane * 4];
    c[0] = f2bf(bf2f(c[0]) + s0);
    c[1] = f2bf(bf2f(c[1]) + s1);
    c[2] = f2bf(bf2f(c[2]) + s2);
    c[3] = f2bf(bf2f(c[3]) + s3);
    *(bf16x4*)&acc[(size_t)row * 512 + lane * 4] = c;
}

extern "C" void kernel_launch(void* const* d_in, const int* in_sizes, int n_in,
                              void* d_out, int out_size, void* d_ws, size_t ws_size,
                              hipStream_t stream)
{
    const float* user_feat = (const float*)d_in[0];
    const float* dish_feat = (const float*)d_in[1];
    const int*   edge_user = (const int*)d_in[2];
    const int*   edge_dish = (const int*)d_in[3];
    const float* W_ui = (const float*)d_in[4];  const float* b_ui = (const float*)d_in[5];
    const float* W_di = (const float*)d_in[6];  const float* b_di = (const float*)d_in[7];
    const float* W_um = (const float*)d_in[8];  const float* b_um = (const float*)d_in[9];
    const float* W_dm = (const float*)d_in[10]; const float* b_dm = (const float*)d_in[11];
    const float* W_uu = (const float*)d_in[12]; const float* b_uu = (const float*)d_in[13];
    const float* W_du = (const float*)d_in[14]; const float* b_du = (const float*)d_in[15];
    const float* W_up = (const float*)d_in[16]; const float* b_up = (const float*)d_in[17];
    const float* W_dp = (const float*)d_in[18]; const float* b_dp = (const float*)d_in[19];

    const int U = in_sizes[0] / D_IN;   // 50000
    const int D = in_sizes[1] / D_IN;   // 10000
    const int E = in_sizes[2];          // 200000

    float* out = (float*)d_out;
    float* user_emb = out;
    float* dish_emb = out + (size_t)U * OUT_D;

    // ---- workspace layout (shorts) ----
    short* sws = (short*)d_ws;
    short* user_buf = sws;                                  // [U][512]: init | msg
    short* dish_buf = user_buf + (size_t)U * 512;           // [D][512]
    short* user_upd = dish_buf + (size_t)D * 512;           // [U][256]
    short* dish_upd = user_upd + (size_t)U * 256;           // [D][256]
    short* Wut  = dish_upd + (size_t)D * 256;               // [512][1024]
    short* Wdt  = Wut  + (size_t)512 * 1024;                // [512][1024]
    short* Wuut = Wdt  + (size_t)512 * 1024;                // [256][256]
    short* Wdut = Wuut + (size_t)256 * 256;                 // [256][256]
    short* Wupt = Wdut + (size_t)256 * 256;                 // [128][256]
    short* Wdpt = Wupt + (size_t)128 * 256;                 // [128][256]
    float* bu   = (float*)(Wdpt + (size_t)128 * 256);       // [512]
    float* bd   = bu + 512;                                 // [512]
    int*   cnt_u  = (int*)(bd + 512);                       // [U]  \ contiguous for
    int*   cnt_d  = cnt_u + U;                              // [D]  / single memset
    int*   offs_u = cnt_d + D;                              // [U]
    int*   offs_d = offs_u + U;                             // [D]
    int*   srcl_u = offs_d + D;                             // [E]
    int*   srcl_d = srcl_u + E;                             // [E]

    // ---- 1: pack all weights + biases ----
    hipLaunchKernelGGL(pack_all, dim3(8, 32, 9), dim3(32, 8), 0, stream,
                       W_ui, W_dm, W_di, W_um, W_uu, W_du, W_up, W_dp,
                       b_ui, b_dm, b_di, b_um,
                       Wut, Wdt, Wuut, Wdut, Wupt, Wdpt, bu, bd);

    // ---- 2-5: CSR build ----
    hipMemsetAsync(cnt_u, 0, (size_t)(U + D) * sizeof(int), stream);
    int eg2 = (2 * E + 255) / 256;
    hipLaunchKernelGGL(hist2, dim3(eg2), dim3(256), 0, stream,
                       edge_user, edge_dish, cnt_u, cnt_d, E);
    hipLaunchKernelGGL(scan2, dim3(2), dim3(1024), 0, stream,
                       cnt_u, offs_u, U, cnt_d, offs_d, D);
    hipLaunchKernelGGL(fill2, dim3(eg2), dim3(256), 0, stream,
                       edge_user, edge_dish, offs_u, srcl_u, offs_d, srcl_d, E);

    const int nbU128 = (U + 127) / 128;   // 391
    const int nbD128 = (D + 127) / 128;   // 79

    // ---- 6: BOTH big fused projections in one launch (f32 A, cvt in staging)
    {
        int nb0 = nbU128 * 4, nb1 = nbD128 * 4;
        hipLaunchKernelGGL((mfma_gemm2<true, true, false>),
                           dim3(nb0 + nb1), dim3(256), 0, stream,
                           user_feat, D_IN, Wut, bu, user_buf, U, 512, D_IN, 4, nb0,
                           dish_feat, D_IN, Wdt, bd, dish_buf, D, 512, D_IN, 4);
    }

    // ---- 7: aggregation, both directions ----
    int nbU = (U + 3) / 4;
    hipLaunchKernelGGL(seg_sum_both, dim3(nbU + (D + 3) / 4), dim3(256), 0, stream,
                       dish_buf + HID, user_buf + HID,
                       srcl_u, offs_u, cnt_u, srcl_d, offs_d, cnt_d,
                       user_buf, dish_buf, U, D, nbU);

    // ---- 8: BOTH updates in one launch (bf16 A, lda=512) ----
    {
        int nb0 = nbU128 * 2, nb1 = nbD128 * 2;
        hipLaunchKernelGGL((mfma_gemm2<true, false, false>),
                           dim3(nb0 + nb1), dim3(256), 0, stream,
                           user_buf, 512, Wuut, b_uu, user_upd, U, HID, HID, 2, nb0,
                           dish_buf, 512, Wdut, b_du, dish_upd, D, HID, HID, 2);
    }

    // ---- 9: BOTH final projections in one launch (f32 out) ----
    {
        int nb0 = nbU128, nb1 = nbD128;
        hipLaunchKernelGGL((mfma_gemm2<false, false, true>),
                           dim3(nb0 + nb1), dim3(256), 0, stream,
                           user_upd, HID, Wupt, b_up, user_emb, U, OUT_D, HID, 1, nb0,
                           dish_upd, HID, Wdpt, b_dp, dish_emb, D, OUT_D, HID, 1);
    }
}

// Round 14
// 349.679 us; speedup vs baseline: 1.8840x; 1.0101x over previous
//
#include <hip/hip_runtime.h>
#include <hip/hip_bf16.h>

// Problem dims
#define D_IN  1024
#define HID   256
#define OUT_D 128

using bf16x8  = __attribute__((ext_vector_type(8))) short;
using bf16x4  = __attribute__((ext_vector_type(4))) short;
using f32x4   = __attribute__((ext_vector_type(4))) float;
typedef unsigned int u32;

__device__ inline float bf2f(short s) {
    unsigned u = ((unsigned)(unsigned short)s) << 16;
    return __uint_as_float(u);
}
__device__ inline short f2bf(float f) {
    __hip_bfloat16 h = __float2bfloat16(f);   // RNE
    return *reinterpret_cast<short*>(&h);
}

// async global->LDS, 16 B per lane (HW: wave-uniform LDS base + lane*16)
__device__ __forceinline__ void gld16(void* lds, const void* g) {
    __builtin_amdgcn_global_load_lds(
        (const __attribute__((address_space(1))) u32*)g,
        (__attribute__((address_space(3))) u32*)lds, 16, 0, 0);
}

// ---------------------------------------------------------------------------
// pack_all: all 8 weight transposes (f32 [K][N] -> bf16 [n][K]) + bias concat
// ---------------------------------------------------------------------------
__global__ void pack_all(
    const float* __restrict__ W_ui, const float* __restrict__ W_dm,
    const float* __restrict__ W_di, const float* __restrict__ W_um,
    const float* __restrict__ W_uu, const float* __restrict__ W_du,
    const float* __restrict__ W_up, const float* __restrict__ W_dp,
    const float* __restrict__ b_ui, const float* __restrict__ b_dm,
    const float* __restrict__ b_di, const float* __restrict__ b_um,
    short* __restrict__ Wut, short* __restrict__ Wdt,
    short* __restrict__ Wuut, short* __restrict__ Wdut,
    short* __restrict__ Wupt, short* __restrict__ Wdpt,
    float* __restrict__ bu, float* __restrict__ bd)
{
    const int z = blockIdx.z;
    const int tx = threadIdx.x, ty = threadIdx.y;
    if (z == 8) {  // biases
        if (blockIdx.x != 0 || blockIdx.y != 0) return;
        int t = ty * 32 + tx;  // 0..255
        bu[t] = b_ui[t]; bu[256 + t] = b_dm[t];
        bd[t] = b_di[t]; bd[256 + t] = b_um[t];
        return;
    }
    const float* in; short* out; int K, N, n_off = 0;
    switch (z) {
        case 0: in = W_ui; out = Wut;  K = 1024; N = 256; n_off = 0;   break;
        case 1: in = W_dm; out = Wut;  K = 1024; N = 256; n_off = 256; break;
        case 2: in = W_di; out = Wdt;  K = 1024; N = 256; n_off = 0;   break;
        case 3: in = W_um; out = Wdt;  K = 1024; N = 256; n_off = 256; break;
        case 4: in = W_uu; out = Wuut; K = 256;  N = 256; break;
        case 5: in = W_du; out = Wdut; K = 256;  N = 256; break;
        case 6: in = W_up; out = Wupt; K = 256;  N = 128; break;
        default:in = W_dp; out = Wdpt; K = 256;  N = 128; break;
    }
    const int n0 = blockIdx.x * 32, k0 = blockIdx.y * 32;
    if (n0 >= N || k0 >= K) return;
    __shared__ float t[32][33];
#pragma unroll
    for (int j = 0; j < 32; j += 8)
        t[ty + j][tx] = in[(size_t)(k0 + ty + j) * N + (n0 + tx)];
    __syncthreads();
#pragma unroll
    for (int j = 0; j < 32; j += 8)
        out[(size_t)(n_off + n0 + ty + j) * K + (k0 + tx)] = f2bf(t[tx][ty + j]);
}

// ---------------------------------------------------------------------------
// Dual MFMA GEMM with TRIPLE-BUFFERED counted-vmcnt pipeline (T3+T4, depth 2).
//   Per K-step t: issue STAGE(buf[(t+2)%3]) | s_waitcnt vmcnt(2*NST)
//   [in-order vmcnt retirement => stage(t)'s loads landed; t+1,t+2 stay in
//   flight across TWO compute phases] | s_barrier | 16 MFMA from buf[t%3] |
//   s_barrier [buffer free for overwrite at t+3].
//   R13 bug fixed: buffer rotation is now a true mod-3 ((bsel+2)%3; the old
//   expression produced buffer index 4 for bsel==2 -> OOB LDS stage).
//   BK=32, BM=BN=128, 256 thr (4 waves 2x2), v_mfma_f32_16x16x32_bf16.
//   LDS: f32-A 3x24KB=72KB (2 blk/CU); bf16-A 3x16KB=48KB (3 blk/CU).
//   gld16: linear LDS dest + pre-swizzled SOURCE (rule #21).
//   Bijective XCD chunk swizzle per sub-grid, n-fastest.
// ---------------------------------------------------------------------------
template <bool RELU, bool AF32, bool CF32>
__global__ __launch_bounds__(256) void mfma_gemm2(
    const void* __restrict__ A0_, int lda0, const short* __restrict__ Wt0,
    const float* __restrict__ bias0, void* __restrict__ C0,
    int M0, int N0, int K0, int nN0, int nb0,
    const void* __restrict__ A1_, int lda1, const short* __restrict__ Wt1,
    const float* __restrict__ bias1, void* __restrict__ C1,
    int M1, int N1, int K1, int nN1)
{
    constexpr int ABYTES = AF32 ? 16384 : 8192;   // 128 rows x 128B / 64B
    constexpr int BBYTES = 8192;                  // 128 rows x 64B
    constexpr int STEP = ABYTES + BBYTES;
    __shared__ __align__(16) char smem[3 * STEP];

    const int tid = threadIdx.x;

    // select GEMM by block range
    const void* A_; const short* Wt; const float* bias; void* Cv;
    int lda, M, N, K, nN, nwg, orig;
    if ((int)blockIdx.x < nb0) {
        A_ = A0_; lda = lda0; Wt = Wt0; bias = bias0; Cv = C0;
        M = M0; N = N0; K = K0; nN = nN0; nwg = nb0; orig = blockIdx.x;
    } else {
        A_ = A1_; lda = lda1; Wt = Wt1; bias = bias1; Cv = C1;
        M = M1; N = N1; K = K1; nN = nN1;
        nwg = gridDim.x - nb0; orig = blockIdx.x - nb0;
    }

    // bijective XCD chunk swizzle (m204) within the sub-grid
    const int qq = nwg >> 3, rr = nwg & 7;
    const int xcd = orig & 7, pos = orig >> 3;
    const int wg = (xcd < rr) ? (xcd * (qq + 1) + pos)
                              : (rr * (qq + 1) + (xcd - rr) * qq + pos);
    const int n0 = (wg % nN) * 128;
    const int m0 = (wg / nN) * 128;

    const int w = tid >> 6, l = tid & 63;
    const int wm = (w >> 1) * 64, wn = (w & 1) * 64;
    const int fr = l & 15, fg = l >> 4;

    f32x4 acc[4][4] = {};

    const char* Ab = (const char*)A_;
    const char* Bb = (const char*)Wt;
    const size_t lda_b = (size_t)lda * (AF32 ? 4 : 2);
    const size_t ldb_b = (size_t)K * 2;

    auto stage = [&](int buf, int k0) {
        char* As = smem + buf * STEP;
        char* Bs = As + ABYTES;
        if constexpr (AF32) {
#pragma unroll
            for (int i = 0; i < 4; ++i) {      // A: 128 rows x 128B f32
                int o = i * 4096 + tid * 16;
                int row = o >> 7, cb = o & 127;
                int scb = cb ^ ((row & 7) << 4);
                int arow = m0 + row; if (arow > M - 1) arow = M - 1;
                gld16(As + o, Ab + (size_t)arow * lda_b + (size_t)k0 * 4 + scb);
            }
        } else {
#pragma unroll
            for (int i = 0; i < 2; ++i) {      // A: 128 rows x 64B bf16
                int o = i * 4096 + tid * 16;
                int row = o >> 6, cb = o & 63;
                int scb = cb ^ ((row & 3) << 4);
                int arow = m0 + row; if (arow > M - 1) arow = M - 1;
                gld16(As + o, Ab + (size_t)arow * lda_b + (size_t)k0 * 2 + scb);
            }
        }
#pragma unroll
        for (int i = 0; i < 2; ++i) {          // B: 128 rows x 64B bf16
            int o = i * 4096 + tid * 16;
            int row = o >> 6, cb = o & 63;
            int scb = cb ^ ((row & 3) << 4);
            gld16(Bs + o, Bb + (size_t)(n0 + row) * ldb_b + (size_t)k0 * 2 + scb);
        }
    };

    const int T = K / 32;                      // 32 (K=1024) or 8 (K=256)

    // ---- prologue: two tiles in flight ----
    stage(0, 0);
    stage(1, 32);

    int bsel = 0;
    for (int t = 0; t < T; ++t) {
        // issue stage(t+2), then counted wait: own stage(t) loads landed
        if (t + 2 < T) {
            int nb2 = bsel + 2; if (nb2 >= 3) nb2 -= 3;   // true mod-3 (R13 fix)
            stage(nb2, (t + 2) * 32);
            __builtin_amdgcn_sched_barrier(0);
            if constexpr (AF32) asm volatile("s_waitcnt vmcnt(12)" ::: "memory");
            else                asm volatile("s_waitcnt vmcnt(8)"  ::: "memory");
        } else if (t + 1 < T) {
            if constexpr (AF32) asm volatile("s_waitcnt vmcnt(6)" ::: "memory");
            else                asm volatile("s_waitcnt vmcnt(4)" ::: "memory");
        } else {
            asm volatile("s_waitcnt vmcnt(0)" ::: "memory");
        }
        __builtin_amdgcn_sched_barrier(0);
        __builtin_amdgcn_s_barrier();          // all waves' tile-t loads landed
        __builtin_amdgcn_sched_barrier(0);

        const char* As = smem + bsel * STEP;
        const char* Bs = As + ABYTES;
        bf16x8 af[4], bfv[4];
#pragma unroll
        for (int i = 0; i < 4; ++i) {
            int row = wm + i * 16 + fr;
            if constexpr (AF32) {
                int sw = (row & 7) << 4;
                const char* rb = As + row * 128;
                f32x4 lo = *reinterpret_cast<const f32x4*>(rb + ((fg * 32) ^ sw));
                f32x4 hi = *reinterpret_cast<const f32x4*>(rb + ((fg * 32 + 16) ^ sw));
                bf16x8 tt;
                tt[0] = f2bf(lo[0]); tt[1] = f2bf(lo[1]);
                tt[2] = f2bf(lo[2]); tt[3] = f2bf(lo[3]);
                tt[4] = f2bf(hi[0]); tt[5] = f2bf(hi[1]);
                tt[6] = f2bf(hi[2]); tt[7] = f2bf(hi[3]);
                af[i] = tt;
            } else {
                int cb = (fg * 16) ^ ((row & 3) << 4);
                af[i] = *reinterpret_cast<const bf16x8*>(As + row * 64 + cb);
            }
        }
#pragma unroll
        for (int j = 0; j < 4; ++j) {
            int row = wn + j * 16 + fr;
            int cb = (fg * 16) ^ ((row & 3) << 4);
            bfv[j] = *reinterpret_cast<const bf16x8*>(Bs + row * 64 + cb);
        }
#pragma unroll
        for (int i = 0; i < 4; ++i)
#pragma unroll
            for (int j = 0; j < 4; ++j)
                acc[i][j] = __builtin_amdgcn_mfma_f32_16x16x32_bf16(
                    af[i], bfv[j], acc[i][j], 0, 0, 0);

        __builtin_amdgcn_sched_barrier(0);
        __builtin_amdgcn_s_barrier();          // reads done; buf free at t+3
        __builtin_amdgcn_sched_barrier(0);

        bsel = (bsel == 2) ? 0 : bsel + 1;
    }

    // epilogue: C/D layout col=lane&15, row=(lane>>4)*4+reg  [m89-verified]
#pragma unroll
    for (int i = 0; i < 4; ++i) {
#pragma unroll
        for (int e = 0; e < 4; ++e) {
            int gm = m0 + wm + i * 16 + fg * 4 + e;
            if (gm >= M) continue;
#pragma unroll
            for (int j = 0; j < 4; ++j) {
                int gn = n0 + wn + j * 16 + fr;
                float v = acc[i][j][e] + bias[gn];
                if (RELU) v = fmaxf(v, 0.f);
                if (CF32) ((float*)Cv)[(size_t)gm * N + gn] = v;
                else      ((short*)Cv)[(size_t)gm * N + gn] = f2bf(v);
            }
        }
    }
}

// ---------------------------------------------------------------------------
// CSR construction, fused: one hist, one scan (2 blocks), one fill
// ---------------------------------------------------------------------------
__global__ void hist2(const int* __restrict__ eu, const int* __restrict__ ed,
                      int* __restrict__ cu, int* __restrict__ cd, int E)
{
    int i = blockIdx.x * blockDim.x + threadIdx.x;
    if (i < E) atomicAdd(&cu[eu[i]], 1);
    else if (i < 2 * E) atomicAdd(&cd[ed[i - E]], 1);
}

__global__ __launch_bounds__(1024) void scan2(
    const int* __restrict__ cnt_u, int* __restrict__ offs_u, int U,
    const int* __restrict__ cnt_d, int* __restrict__ offs_d, int D)
{
    const int* cnt = (blockIdx.x == 0) ? cnt_u : cnt_d;
    int* offs      = (blockIdx.x == 0) ? offs_u : offs_d;
    const int n    = (blockIdx.x == 0) ? U : D;

    __shared__ int tsum[1024];
    const int t = threadIdx.x;
    const int chunk = (n + 1023) / 1024;
    const int lo = t * chunk;
    const int hi = min(lo + chunk, n);
    int s = 0;
    for (int i = lo; i < hi; ++i) s += cnt[i];
    tsum[t] = s;
    __syncthreads();
    for (int d = 1; d < 1024; d <<= 1) {
        int v = (t >= d) ? tsum[t - d] : 0;
        __syncthreads();
        tsum[t] += v;
        __syncthreads();
    }
    int run = (t > 0) ? tsum[t - 1] : 0;
    for (int i = lo; i < hi; ++i) {
        offs[i] = run;
        run += cnt[i];
    }
}

// mutates offs -> segment END; srclist grouped by dst
__global__ void fill2(const int* __restrict__ eu, const int* __restrict__ ed,
                      int* __restrict__ offs_u, int* __restrict__ srcl_u,
                      int* __restrict__ offs_d, int* __restrict__ srcl_d, int E)
{
    int i = blockIdx.x * blockDim.x + threadIdx.x;
    if (i < E) {
        int p = atomicAdd(&offs_u[eu[i]], 1);
        srcl_u[p] = ed[i];
    } else if (i < 2 * E) {
        int k = i - E;
        int p = atomicAdd(&offs_d[ed[k]], 1);
        srcl_d[p] = eu[k];
    }
}

// ---------------------------------------------------------------------------
// Segment sum, both directions in one launch; 1 wave/row, 4-deep gather unroll
// ---------------------------------------------------------------------------
__global__ __launch_bounds__(256) void seg_sum_both(
    const short* __restrict__ dish_msg, const short* __restrict__ user_msg,
    const int* __restrict__ srcl_u, const int* __restrict__ offs_u,
    const int* __restrict__ cnt_u,
    const int* __restrict__ srcl_d, const int* __restrict__ offs_d,
    const int* __restrict__ cnt_d,
    short* __restrict__ user_buf, short* __restrict__ dish_buf,
    int U, int D, int nbU)
{
    const short* msg; const int *sl, *oe, *ct; short* acc; int nRows, rb;
    if (blockIdx.x < nbU) {
        msg = dish_msg; sl = srcl_u; oe = offs_u; ct = cnt_u;
        acc = user_buf; nRows = U; rb = blockIdx.x;
    } else {
        msg = user_msg; sl = srcl_d; oe = offs_d; ct = cnt_d;
        acc = dish_buf; nRows = D; rb = blockIdx.x - nbU;
    }
    int row = rb * 4 + (threadIdx.x >> 6);
    if (row >= nRows) return;
    const int lane = threadIdx.x & 63;
    const int deg = ct[row];
    if (deg == 0) return;
    const int base = oe[row] - deg;

    float s0 = 0.f, s1 = 0.f, s2 = 0.f, s3 = 0.f;
    int j = 0;
    for (; j + 4 <= deg; j += 4) {
        int i0 = sl[base + j], i1 = sl[base + j + 1];
        int i2 = sl[base + j + 2], i3 = sl[base + j + 3];
        bf16x4 v0 = *(const bf16x4*)&msg[(size_t)i0 * 512 + lane * 4];
        bf16x4 v1 = *(const bf16x4*)&msg[(size_t)i1 * 512 + lane * 4];
        bf16x4 v2 = *(const bf16x4*)&msg[(size_t)i2 * 512 + lane * 4];
        bf16x4 v3 = *(const bf16x4*)&msg[(size_t)i3 * 512 + lane * 4];
        s0 += bf2f(v0[0]) + bf2f(v1[0]) + bf2f(v2[0]) + bf2f(v3[0]);
        s1 += bf2f(v0[1]) + bf2f(v1[1]) + bf2f(v2[1]) + bf2f(v3[1]);
        s2 += bf2f(v0[2]) + bf2f(v1[2]) + bf2f(v2[2]) + bf2f(v3[2]);
        s3 += bf2f(v0[3]) + bf2f(v1[3]) + bf2f(v2[3]) + bf2f(v3[3]);
    }
    for (; j < deg; ++j) {
        int i0 = sl[base + j];
        bf16x4 v = *(const bf16x4*)&msg[(size_t)i0 * 512 + lane * 4];
        s0 += bf2f(v[0]); s1 += bf2f(v[1]); s2 += bf2f(v[2]); s3 += bf2f(v[3]);
    }
    bf16x4 c = *(bf16x4*)&acc[(size_t)row * 512 + lane * 4];
    c[0] = f2bf(bf2f(c[0]) + s0);
    c[1] = f2bf(bf2f(c[1]) + s1);
    c[2] = f2bf(bf2f(c[2]) + s2);
    c[3] = f2bf(bf2f(c[3]) + s3);
    *(bf16x4*)&acc[(size_t)row * 512 + lane * 4] = c;
}

extern "C" void kernel_launch(void* const* d_in, const int* in_sizes, int n_in,
                              void* d_out, int out_size, void* d_ws, size_t ws_size,
                              hipStream_t stream)
{
    const float* user_feat = (const float*)d_in[0];
    const float* dish_feat = (const float*)d_in[1];
    const int*   edge_user = (const int*)d_in[2];
    const int*   edge_dish = (const int*)d_in[3];
    const float* W_ui = (const float*)d_in[4];  const float* b_ui = (const float*)d_in[5];
    const float* W_di = (const float*)d_in[6];  const float* b_di = (const float*)d_in[7];
    const float* W_um = (const float*)d_in[8];  const float* b_um = (const float*)d_in[9];
    const float* W_dm = (const float*)d_in[10]; const float* b_dm = (const float*)d_in[11];
    const float* W_uu = (const float*)d_in[12]; const float* b_uu = (const float*)d_in[13];
    const float* W_du = (const float*)d_in[14]; const float* b_du = (const float*)d_in[15];
    const float* W_up = (const float*)d_in[16]; const float* b_up = (const float*)d_in[17];
    const float* W_dp = (const float*)d_in[18]; const float* b_dp = (const float*)d_in[19];

    const int U = in_sizes[0] / D_IN;   // 50000
    const int D = in_sizes[1] / D_IN;   // 10000
    const int E = in_sizes[2];          // 200000

    float* out = (float*)d_out;
    float* user_emb = out;
    float* dish_emb = out + (size_t)U * OUT_D;

    // ---- workspace layout (shorts) ----
    short* sws = (short*)d_ws;
    short* user_buf = sws;                                  // [U][512]: init | msg
    short* dish_buf = user_buf + (size_t)U * 512;           // [D][512]
    short* user_upd = dish_buf + (size_t)D * 512;           // [U][256]
    short* dish_upd = user_upd + (size_t)U * 256;           // [D][256]
    short* Wut  = dish_upd + (size_t)D * 256;               // [512][1024]
    short* Wdt  = Wut  + (size_t)512 * 1024;                // [512][1024]
    short* Wuut = Wdt  + (size_t)512 * 1024;                // [256][256]
    short* Wdut = Wuut + (size_t)256 * 256;                 // [256][256]
    short* Wupt = Wdut + (size_t)256 * 256;                 // [128][256]
    short* Wdpt = Wupt + (size_t)128 * 256;                 // [128][256]
    float* bu   = (float*)(Wdpt + (size_t)128 * 256);       // [512]
    float* bd   = bu + 512;                                 // [512]
    int*   cnt_u  = (int*)(bd + 512);                       // [U]  \ contiguous for
    int*   cnt_d  = cnt_u + U;                              // [D]  / single memset
    int*   offs_u = cnt_d + D;                              // [U]
    int*   offs_d = offs_u + U;                             // [D]
    int*   srcl_u = offs_d + D;                             // [E]
    int*   srcl_d = srcl_u + E;                             // [E]

    // ---- 1: pack all weights + biases ----
    hipLaunchKernelGGL(pack_all, dim3(8, 32, 9), dim3(32, 8), 0, stream,
                       W_ui, W_dm, W_di, W_um, W_uu, W_du, W_up, W_dp,
                       b_ui, b_dm, b_di, b_um,
                       Wut, Wdt, Wuut, Wdut, Wupt, Wdpt, bu, bd);

    // ---- 2-5: CSR build ----
    hipMemsetAsync(cnt_u, 0, (size_t)(U + D) * sizeof(int), stream);
    int eg2 = (2 * E + 255) / 256;
    hipLaunchKernelGGL(hist2, dim3(eg2), dim3(256), 0, stream,
                       edge_user, edge_dish, cnt_u, cnt_d, E);
    hipLaunchKernelGGL(scan2, dim3(2), dim3(1024), 0, stream,
                       cnt_u, offs_u, U, cnt_d, offs_d, D);
    hipLaunchKernelGGL(fill2, dim3(eg2), dim3(256), 0, stream,
                       edge_user, edge_dish, offs_u, srcl_u, offs_d, srcl_d, E);

    const int nbU128 = (U + 127) / 128;   // 391
    const int nbD128 = (D + 127) / 128;   // 79

    // ---- 6: BOTH big fused projections in one launch (f32 A, cvt in staging)
    {
        int nb0 = nbU128 * 4, nb1 = nbD128 * 4;
        hipLaunchKernelGGL((mfma_gemm2<true, true, false>),
                           dim3(nb0 + nb1), dim3(256), 0, stream,
                           user_feat, D_IN, Wut, bu, user_buf, U, 512, D_IN, 4, nb0,
                           dish_feat, D_IN, Wdt, bd, dish_buf, D, 512, D_IN, 4);
    }

    // ---- 7: aggregation, both directions ----
    int nbU = (U + 3) / 4;
    hipLaunchKernelGGL(seg_sum_both, dim3(nbU + (D + 3) / 4), dim3(256), 0, stream,
                       dish_buf + HID, user_buf + HID,
                       srcl_u, offs_u, cnt_u, srcl_d, offs_d, cnt_d,
                       user_buf, dish_buf, U, D, nbU);

    // ---- 8: BOTH updates in one launch (bf16 A, lda=512) ----
    {
        int nb0 = nbU128 * 2, nb1 = nbD128 * 2;
        hipLaunchKernelGGL((mfma_gemm2<true, false, false>),
                           dim3(nb0 + nb1), dim3(256), 0, stream,
                           user_buf, 512, Wuut, b_uu, user_upd, U, HID, HID, 2, nb0,
                           dish_buf, 512, Wdut, b_du, dish_upd, D, HID, HID, 2);
    }

    // ---- 9: BOTH final projections in one launch (f32 out) ----
    {
        int nb0 = nbU128, nb1 = nbD128;
        hipLaunchKernelGGL((mfma_gemm2<false, false, true>),
                           dim3(nb0 + nb1), dim3(256), 0, stream,
                           user_upd, HID, Wupt, b_up, user_emb, U, OUT_D, HID, 1, nb0,
                           dish_upd, HID, Wdpt, b_dp, dish_emb, D, OUT_D, HID, 1);
    }
}